// Round 10
// baseline (87.153 us; speedup 1.0000x reference)
//
#include <hip/hip_runtime.h>
#include <math.h>

// Problem constants (fixed shapes from reference)
#define N_  4
#define C_  64
#define H_  28
#define W_  28
#define F_  64
#define KK  576            // C_ * 3 * 3
#define NX  (N_*C_*H_*W_)  // 200704
#define NX4 (NX/4)         // 50176 float4s

#define XCH 52             // Xs floats per channel: 3 rows x 16 + 4 pad.
                           // 52 % 32 == 20 -> the 4 per-wave channel bases hit
                           // disjoint bank quads: conflict-free b128.

// ws float layout:
// [0..255]    per-block partial min of x (256 blocks)
// [256..511]  per-block partial max of x
// [512..]     Wt[576*64]  dequantized W, k-major: Wt[(c*9+k)*64 + f]

// ---------------------------------------------------------------------------
// Kernel 1: grid 256 x 256.
//   All blocks: partial min/max of x (ONE float4 per thread - latency-min).
//   Blocks 0..15 additionally: fake-quant+dequant 4 filters (1 per wave),
//   write k-major Wt into ws.
// ---------------------------------------------------------------------------
__global__ __launch_bounds__(256) void k_prep(const float* __restrict__ x,
                                              const float* __restrict__ Wg,
                                              float* __restrict__ ws) {
  __shared__ float sm[4], sM[4];
  int tid = threadIdx.x, lane = tid & 63, wv = tid >> 6;

  const float4* x4 = (const float4*)x;
  int gid = blockIdx.x * 256 + tid;
  float m = 3.4e38f, M = -3.4e38f;
  if (gid < NX4) {
    float4 v = x4[gid];
    m = fminf(fminf(v.x, v.y), fminf(v.z, v.w));
    M = fmaxf(fmaxf(v.x, v.y), fmaxf(v.z, v.w));
  }
  #pragma unroll
  for (int o = 32; o; o >>= 1) {
    m = fminf(m, __shfl_xor(m, o));
    M = fmaxf(M, __shfl_xor(M, o));
  }
  if (lane == 0) { sm[wv] = m; sM[wv] = M; }
  __syncthreads();
  if (tid == 0) {
    m = fminf(fminf(sm[0], sm[1]), fminf(sm[2], sm[3]));
    M = fmaxf(fmaxf(sM[0], sM[1]), fmaxf(sM[2], sM[3]));
    ws[blockIdx.x] = m;
    ws[256 + blockIdx.x] = M;
  }

  if (blockIdx.x < 16) {
    int f = blockIdx.x * 4 + wv;
    const float* wp = Wg + f * KK;
    float v[9];
    float wm = 3.4e38f, wM = -3.4e38f;
    #pragma unroll
    for (int u = 0; u < 9; ++u) {
      v[u] = wp[lane + 64 * u];
      wm = fminf(wm, v[u]);
      wM = fmaxf(wM, v[u]);
    }
    #pragma unroll
    for (int o = 32; o; o >>= 1) {
      wm = fminf(wm, __shfl_xor(wm, o));
      wM = fmaxf(wM, __shfl_xor(wM, o));
    }
    float s = fmaxf((wM - wm) / 255.0f, 1e-12f);
    float z = rintf(-wm / s);
    float rs = 1.0f / s;
    float* Wt = ws + 512;
    #pragma unroll
    for (int u = 0; u < 9; ++u) {
      float q = fminf(fmaxf(rintf(v[u] * rs) + z, 0.0f), 255.0f);
      Wt[(lane + 64 * u) * 64 + f] = (q - z) * s;
    }
  }
}

// ---------------------------------------------------------------------------
// Kernel 2: grid (y=28, n=4, z=4: fh = z>>1, colh = z&1) = 448 blocks (2/CU).
//   Block: 32 filters x 14 cols, all 64 channels. Thread (fl, cq):
//   filters f0 = fh*32+fl, f1 = f0+16; channels c = cq + 16*ci; 14 cols.
//   ALL 72 W values hoisted into registers before staging (latency hidden
//   behind phase B). X from LDS, conflict-free b128. 43.3 KB LDS.
//   Summation order identical to R6 -> bitwise-identical output.
// ---------------------------------------------------------------------------
__global__ __launch_bounds__(256, 2) void k_main(const float* __restrict__ x,
                                                 const float* __restrict__ ws,
                                                 float* __restrict__ out) {
  __shared__ __align__(16) float Xs[64 * XCH];      // 13.3 KB quantized x slab
  __shared__ float Rbuf[16 * 32 * 15];              // 30 KB [cq][f_local][col pad 15]
  int tid = threadIdx.x;
  int lane = tid & 63;
  int fl = tid & 15, cq = tid >> 4;
  int y = blockIdx.x, n = blockIdx.y;
  int fh = blockIdx.z >> 1, colh = blockIdx.z & 1;
  int bc = colh * 14;                               // first output col of this block

  // --- Hoisted W loads: all 4 channel-chunks, 2 filters each (72 floats).
  //     Issued first so L2 latency hides behind phases A+B.
  const float* Wt = ws + 512;
  int f0 = fh * 32 + fl;                            // second filter = f0 + 16
  float wall[72];
  #pragma unroll
  for (int ci = 0; ci < 4; ++ci) {
    const float* wp = Wt + ((cq + 16 * ci) * 9) * 64 + f0;
    #pragma unroll
    for (int k = 0; k < 9; ++k) {
      wall[ci * 18 + k]     = wp[k * 64];
      wall[ci * 18 + 9 + k] = wp[k * 64 + 16];
    }
  }

  // --- Phase A: x scale/zp from 256 partials (float4 per lane + butterfly) ---
  const float4* mp = (const float4*)ws;
  float4 mv = mp[lane], Mv = mp[64 + lane];
  float m = fminf(fminf(mv.x, mv.y), fminf(mv.z, mv.w));
  float M = fmaxf(fmaxf(Mv.x, Mv.y), fmaxf(Mv.z, Mv.w));
  #pragma unroll
  for (int o = 32; o; o >>= 1) {
    m = fminf(m, __shfl_xor(m, o));
    M = fmaxf(M, __shfl_xor(M, o));
  }
  float sx = fmaxf((M - m) / 65535.0f, 1e-12f);
  float zx = rintf(-m / sx);
  float rx = 1.0f / sx;

  // --- Phase B: stage quantized X, 64 ch x 3 rows x 16 cols (bc-1 .. bc+14) ---
  {
    int j = tid & 15, sub = tid >> 4;               // 16 (c,r) pairs per pass
    #pragma unroll
    for (int it = 0; it < 12; ++it) {
      int cr = sub + 16 * it;                       // 0..191
      int c = cr / 3, r = cr - c * 3;
      int row = y + r - 1, col = bc - 1 + j;
      float v = 0.0f;
      if ((unsigned)row < 28u && (unsigned)col < 28u) {
        float raw = x[((n * 64 + c) * 28 + row) * 28 + col];
        float q = fminf(fmaxf(rintf(raw * rx) + zx, 0.0f), 65535.0f);
        v = (q - zx) * sx;
      }
      Xs[c * XCH + r * 16 + j] = v;
    }
  }
  __syncthreads();

  // --- Phase C: main loop (pure LDS + VALU; W already in registers) ---
  float acc0[14], acc1[14];
  #pragma unroll
  for (int i = 0; i < 14; ++i) { acc0[i] = 0.0f; acc1[i] = 0.0f; }

  #pragma unroll
  for (int ci = 0; ci < 4; ++ci) {
    int c = cq + 16 * ci;
    #pragma unroll
    for (int r = 0; r < 3; ++r) {
      const float4* xr4 = (const float4*)&Xs[c * XCH + r * 16];
      float xv[16];
      #pragma unroll
      for (int i = 0; i < 4; ++i) ((float4*)xv)[i] = xr4[i];
      float wa0 = wall[ci * 18 + 3 * r], wa1 = wall[ci * 18 + 3 * r + 1], wa2 = wall[ci * 18 + 3 * r + 2];
      float wb0 = wall[ci * 18 + 9 + 3 * r], wb1 = wall[ci * 18 + 9 + 3 * r + 1], wb2 = wall[ci * 18 + 9 + 3 * r + 2];
      #pragma unroll
      for (int p = 0; p < 14; ++p) {
        acc0[p] += fabsf(wa0 - xv[p]) + fabsf(wa1 - xv[p + 1]) + fabsf(wa2 - xv[p + 2]);
        acc1[p] += fabsf(wb0 - xv[p]) + fabsf(wb1 - xv[p + 1]) + fabsf(wb2 - xv[p + 2]);
      }
    }
  }

  // --- Phase E: write 16 cq-partials, one barrier, gather ---
  #pragma unroll
  for (int p = 0; p < 14; ++p) {
    Rbuf[(cq * 32 + fl) * 15 + p]      = acc0[p];
    Rbuf[(cq * 32 + 16 + fl) * 15 + p] = acc1[p];
  }
  __syncthreads();

  // 448 outputs (32 f x 14 cols) / 256 threads
  #pragma unroll
  for (int i = 0; i < 2; ++i) {
    int idx = tid + 256 * i;
    if (idx < 448) {
      int ff = idx / 14, col = idx - ff * 14;
      float s = 0.0f;
      #pragma unroll
      for (int q = 0; q < 16; ++q) s += Rbuf[(q * 32 + ff) * 15 + col];
      out[((n * 64 + fh * 32 + ff) * 28 + y) * 28 + bc + col] = -s;
    }
  }
}

extern "C" void kernel_launch(void* const* d_in, const int* in_sizes, int n_in,
                              void* d_out, int out_size, void* d_ws, size_t ws_size,
                              hipStream_t stream) {
  const float* x  = (const float*)d_in[0];
  const float* Wg = (const float*)d_in[1];
  float* out = (float*)d_out;
  float* ws  = (float*)d_ws;

  hipLaunchKernelGGL(k_prep, dim3(256), dim3(256), 0, stream, x, Wg, ws);
  hipLaunchKernelGGL(k_main, dim3(28, 4, 4), dim3(256), 0, stream, x, ws, out);
}

// Round 11
// 73.065 us; speedup vs baseline: 1.1928x; 1.1928x over previous
//
#include <hip/hip_runtime.h>
#include <math.h>

// Problem constants (fixed shapes from reference)
#define N_  4
#define C_  64
#define H_  28
#define W_  28
#define F_  64
#define KK  576            // C_ * 3 * 3
#define NX  (N_*C_*H_*W_)  // 200704
#define NX4 (NX/4)         // 50176 float4s

#define XCH 52             // Xs floats per channel: 3 rows x 16 + 4 pad.
                           // 52 % 32 == 20 -> the 4 per-wave channel bases hit
                           // disjoint bank quads: conflict-free b128.

// ws float layout:
// [0..255]    per-block partial min of x (256 blocks)
// [256..511]  per-block partial max of x
// [512..]     Wt[576*64]  dequantized W, k-major: Wt[(c*9+k)*64 + f]

// ---------------------------------------------------------------------------
// Kernel 1: grid 256 x 256.
//   All blocks: partial min/max of x (ONE float4 per thread - latency-min).
//   Blocks 0..15 additionally: fake-quant+dequant 4 filters (1 per wave),
//   write k-major Wt into ws.
// ---------------------------------------------------------------------------
__global__ __launch_bounds__(256) void k_prep(const float* __restrict__ x,
                                              const float* __restrict__ Wg,
                                              float* __restrict__ ws) {
  __shared__ float sm[4], sM[4];
  int tid = threadIdx.x, lane = tid & 63, wv = tid >> 6;

  const float4* x4 = (const float4*)x;
  int gid = blockIdx.x * 256 + tid;
  float m = 3.4e38f, M = -3.4e38f;
  if (gid < NX4) {
    float4 v = x4[gid];
    m = fminf(fminf(v.x, v.y), fminf(v.z, v.w));
    M = fmaxf(fmaxf(v.x, v.y), fmaxf(v.z, v.w));
  }
  #pragma unroll
  for (int o = 32; o; o >>= 1) {
    m = fminf(m, __shfl_xor(m, o));
    M = fmaxf(M, __shfl_xor(M, o));
  }
  if (lane == 0) { sm[wv] = m; sM[wv] = M; }
  __syncthreads();
  if (tid == 0) {
    m = fminf(fminf(sm[0], sm[1]), fminf(sm[2], sm[3]));
    M = fmaxf(fmaxf(sM[0], sM[1]), fmaxf(sM[2], sM[3]));
    ws[blockIdx.x] = m;
    ws[256 + blockIdx.x] = M;
  }

  if (blockIdx.x < 16) {
    int f = blockIdx.x * 4 + wv;
    const float* wp = Wg + f * KK;
    float v[9];
    float wm = 3.4e38f, wM = -3.4e38f;
    #pragma unroll
    for (int u = 0; u < 9; ++u) {
      v[u] = wp[lane + 64 * u];
      wm = fminf(wm, v[u]);
      wM = fmaxf(wM, v[u]);
    }
    #pragma unroll
    for (int o = 32; o; o >>= 1) {
      wm = fminf(wm, __shfl_xor(wm, o));
      wM = fmaxf(wM, __shfl_xor(wM, o));
    }
    float s = fmaxf((wM - wm) / 255.0f, 1e-12f);
    float z = rintf(-wm / s);
    float rs = 1.0f / s;
    float* Wt = ws + 512;
    #pragma unroll
    for (int u = 0; u < 9; ++u) {
      float q = fminf(fmaxf(rintf(v[u] * rs) + z, 0.0f), 255.0f);
      Wt[(lane + 64 * u) * 64 + f] = (q - z) * s;
    }
  }
}

// ---------------------------------------------------------------------------
// Kernel 2: R6 body. Grid (y=28, n=4, z=4: fh = z>>1, colh = z&1) = 448
//   blocks (2/CU). Block: 32 filters x 14 cols, all 64 channels.
//   Thread (fl, cq): filters f0 = fh*32+fl, f1 = f0+16; channels
//   c = cq + 16*ci; 14 cols. W double-buffered from L2 in wc[18]/wn[18]
//   (~75 live floats: NO spill at the 128-VGPR tier; hoisting all 72 W
//   values in R10 spilled 71 MB/dispatch). X from LDS, conflict-free b128.
// ---------------------------------------------------------------------------
__global__ __launch_bounds__(256, 2) void k_main(const float* __restrict__ x,
                                                 const float* __restrict__ ws,
                                                 float* __restrict__ out) {
  __shared__ __align__(16) float Xs[64 * XCH];      // 13.3 KB quantized x slab
  __shared__ float Rbuf[16 * 32 * 15];              // 30 KB [cq][f_local][col pad 15]
  int tid = threadIdx.x;
  int lane = tid & 63;
  int fl = tid & 15, cq = tid >> 4;
  int y = blockIdx.x, n = blockIdx.y;
  int fh = blockIdx.z >> 1, colh = blockIdx.z & 1;
  int bc = colh * 14;                               // first output col of this block

  // --- Phase A: x scale/zp from 256 partials (float4 per lane + butterfly) ---
  const float4* mp = (const float4*)ws;
  float4 mv = mp[lane], Mv = mp[64 + lane];
  float m = fminf(fminf(mv.x, mv.y), fminf(mv.z, mv.w));
  float M = fmaxf(fmaxf(Mv.x, Mv.y), fmaxf(Mv.z, Mv.w));
  #pragma unroll
  for (int o = 32; o; o >>= 1) {
    m = fminf(m, __shfl_xor(m, o));
    M = fmaxf(M, __shfl_xor(M, o));
  }
  float sx = fmaxf((M - m) / 65535.0f, 1e-12f);
  float zx = rintf(-m / sx);
  float rx = 1.0f / sx;

  // --- Phase B: stage quantized X, 64 ch x 3 rows x 16 cols (bc-1 .. bc+14) ---
  {
    int j = tid & 15, sub = tid >> 4;               // 16 (c,r) pairs per pass
    #pragma unroll
    for (int it = 0; it < 12; ++it) {
      int cr = sub + 16 * it;                       // 0..191
      int c = cr / 3, r = cr - c * 3;
      int row = y + r - 1, col = bc - 1 + j;
      float v = 0.0f;
      if ((unsigned)row < 28u && (unsigned)col < 28u) {
        float raw = x[((n * 64 + c) * 28 + row) * 28 + col];
        float q = fminf(fmaxf(rintf(raw * rx) + zx, 0.0f), 65535.0f);
        v = (q - zx) * sx;
      }
      Xs[c * XCH + r * 16 + j] = v;
    }
  }
  __syncthreads();

  // --- Phase C: main loop (W double-buffered in-loop; X from LDS) ---
  const float* Wt = ws + 512;
  int f0 = fh * 32 + fl;                            // second filter = f0 + 16
  float acc0[14], acc1[14];
  #pragma unroll
  for (int i = 0; i < 14; ++i) { acc0[i] = 0.0f; acc1[i] = 0.0f; }

  float wc[18], wn[18];
  {
    const float* wp = Wt + (cq * 9) * 64 + f0;
    #pragma unroll
    for (int k = 0; k < 9; ++k) { wn[k] = wp[k * 64]; wn[9 + k] = wp[k * 64 + 16]; }
  }

  for (int ci = 0; ci < 4; ++ci) {
    #pragma unroll
    for (int k = 0; k < 18; ++k) wc[k] = wn[k];
    if (ci < 3) {
      const float* wp = Wt + ((cq + 16 * (ci + 1)) * 9) * 64 + f0;
      #pragma unroll
      for (int k = 0; k < 9; ++k) { wn[k] = wp[k * 64]; wn[9 + k] = wp[k * 64 + 16]; }
    }
    int c = cq + 16 * ci;
    #pragma unroll
    for (int r = 0; r < 3; ++r) {
      const float4* xr4 = (const float4*)&Xs[c * XCH + r * 16];
      float xv[16];
      #pragma unroll
      for (int i = 0; i < 4; ++i) ((float4*)xv)[i] = xr4[i];
      float wa0 = wc[3 * r], wa1 = wc[3 * r + 1], wa2 = wc[3 * r + 2];
      float wb0 = wc[9 + 3 * r], wb1 = wc[9 + 3 * r + 1], wb2 = wc[9 + 3 * r + 2];
      #pragma unroll
      for (int p = 0; p < 14; ++p) {
        acc0[p] += fabsf(wa0 - xv[p]) + fabsf(wa1 - xv[p + 1]) + fabsf(wa2 - xv[p + 2]);
        acc1[p] += fabsf(wb0 - xv[p]) + fabsf(wb1 - xv[p + 1]) + fabsf(wb2 - xv[p + 2]);
      }
    }
  }

  // --- Phase E: write 16 cq-partials, one barrier, gather ---
  #pragma unroll
  for (int p = 0; p < 14; ++p) {
    Rbuf[(cq * 32 + fl) * 15 + p]      = acc0[p];
    Rbuf[(cq * 32 + 16 + fl) * 15 + p] = acc1[p];
  }
  __syncthreads();

  // 448 outputs (32 f x 14 cols) / 256 threads
  #pragma unroll
  for (int i = 0; i < 2; ++i) {
    int idx = tid + 256 * i;
    if (idx < 448) {
      int ff = idx / 14, col = idx - ff * 14;
      float s = 0.0f;
      #pragma unroll
      for (int q = 0; q < 16; ++q) s += Rbuf[(q * 32 + ff) * 15 + col];
      out[((n * 64 + fh * 32 + ff) * 28 + y) * 28 + bc + col] = -s;
    }
  }
}

extern "C" void kernel_launch(void* const* d_in, const int* in_sizes, int n_in,
                              void* d_out, int out_size, void* d_ws, size_t ws_size,
                              hipStream_t stream) {
  const float* x  = (const float*)d_in[0];
  const float* Wg = (const float*)d_in[1];
  float* out = (float*)d_out;
  float* ws  = (float*)d_ws;

  hipLaunchKernelGGL(k_prep, dim3(256), dim3(256), 0, stream, x, Wg, ws);
  hipLaunchKernelGGL(k_main, dim3(28, 4, 4), dim3(256), 0, stream, x, ws, out);
}